// Round 9
// baseline (329.639 us; speedup 1.0000x reference)
//
#include <hip/hip_runtime.h>
#include <math.h>

#define TW 16                // tile width  (output cols)
#define TH 32                // tile height (output rows)
#define HR (TH + 10)         // 42 halo rows
#define SSTRIDE 29           // s1/s2 row stride: ODD -> conflict-clean b32 (verified r5)
#define HSTRIDE 66           // hbuf row stride: [mu 0..15 | mv 16..31 | qu 32..47 | qv 48..63 | pad]
                             // ph3: 66*4=264 mod 32 = 8 -> row-group bases {0,8,16,24} -> 2-way (free)
#define SC1 0.0001f
#define SC2 0.0009f
#define PLANES 48
#define NSLOT 64

// u/v transform staged at load: s1=u=a+b, s2=v=a-b. 4 windowed quantities
// (mu,mv,qu,qv) recover everything: 2mu1mu2=(MU^2-MV^2)/2, mu1^2+mu2^2=(MU^2+MV^2)/2,
// E[x2]+E[y2]=(QU+QV)/2, 2E[xy]=(QU-QV)/2.  (epilogue verified exact in r8)
struct SmemT {
    float s1[HR][SSTRIDE];   // 4872 B (u)
    float s2[HR][SSTRIDE];   // 4872 B (v)
    float hbuf[HR][HSTRIDE]; // 11088 B
    float rbuf[8];
};                           // 20864 B -> alloc 20992 -> 7 blocks/CU

// NOTE: __launch_bounds__(256,5). min-waves=6 forces VGPR 48->40 and spills
// to scratch (WRITE_SIZE 62->296 MB, measured rounds 3 AND 5).
// NOTE: keep ALL 256 threads active in phase 2 (r8: 168 threads -> 190 us regression).
__device__ __forceinline__ void ssim_tile(
        SmemT* sm,
        const float* __restrict__ p1, const float* __restrict__ p2,
        int H, int W, int tx, int ty, int level,
        const float* __restrict__ window,
        float* __restrict__ accum,
        float* __restrict__ l1a, float* __restrict__ l1b,   // plane-offset outs (or null)
        float* __restrict__ l2a, float* __restrict__ l2b,
        float* __restrict__ l3a, float* __restrict__ l3b,
        float* __restrict__ l4a, float* __restrict__ l4b)
{
    const int tid = threadIdx.x;

    // 1D gaussian from 2D window: g[k] = w2[5][k]/sqrt(w2[5][5])
    float g[11];
    {
        float invg5 = 1.0f / sqrtf(window[60]);
        #pragma unroll
        for (int k = 0; k < 11; ++k) g[k] = window[55 + k] * invg5;
    }

    // ---- Phase 1: stage halo tile (42 x 28) as u=a+b, v=a-b ----
    for (int s = tid; s < HR * 14; s += 256) {
        int r = s / 14, j = s - r * 14;
        int gy = ty + r - 5;
        int gx = tx - 6 + 2 * j;
        float2 v1 = make_float2(0.f, 0.f), v2 = make_float2(0.f, 0.f);
        if ((unsigned)gy < (unsigned)H && (unsigned)gx < (unsigned)W) {
            size_t o = (size_t)gy * W + gx;
            v1 = *(const float2*)(p1 + o);
            v2 = *(const float2*)(p2 + o);
        }
        sm->s1[r][2 * j]     = v1.x + v2.x;
        sm->s1[r][2 * j + 1] = v1.y + v2.y;
        sm->s2[r][2 * j]     = v1.x - v2.x;
        sm->s2[r][2 * j + 1] = v1.y - v2.y;
    }
    __syncthreads();

    // ---- Fused 2x2 avg-pool -> l1 (a = (u+v)/2, so pool_a = (Su+Sv)/8) ----
    if (l1a && tid < 128) {
        int pc = tid & 7;          // pooled col 0..7
        int pr = tid >> 3;         // pooled row 0..15
        int r  = 2 * pr + 5;
        int jj = 2 * pc + 6;
        float su = (sm->s1[r][jj] + sm->s1[r][jj + 1]) +
                   (sm->s1[r + 1][jj] + sm->s1[r + 1][jj + 1]);
        float sv = (sm->s2[r][jj] + sm->s2[r][jj + 1]) +
                   (sm->s2[r + 1][jj] + sm->s2[r + 1][jj + 1]);
        int W2 = W >> 1;
        size_t o = (size_t)((ty >> 1) + pr) * W2 + (tx >> 1) + pc;
        l1a[o] = 0.125f * (su + sv);
        l1b[o] = 0.125f * (su - sv);
    }

    // ---- Pyramid l2/l3/l4 on wave 3 lanes 0..31 (also runs phase 2 after) ----
    if (l1a && tid >= 192 && tid < 224) {
        const int lane = tid - 192;
        int qr = lane >> 2, qc = lane & 3;      // l2 px = 4x4 mean of originals
        int rb = 4 * qr + 5, cb = 4 * qc + 6;
        float su = 0.f, sv = 0.f;
        #pragma unroll
        for (int i = 0; i < 4; ++i)
            #pragma unroll
            for (int j = 0; j < 4; ++j) {
                su += sm->s1[rb + i][cb + j];
                sv += sm->s2[rb + i][cb + j];
            }
        float v2a = 0.03125f * (su + sv), v2b = 0.03125f * (su - sv);
        {
            int W4 = W >> 2;
            size_t o = (size_t)((ty >> 2) + qr) * W4 + (tx >> 2) + qc;
            l2a[o] = v2a;
            l2b[o] = v2b;
        }
        float v3a, v3b;
        {
            int tr = (lane >> 1) & 3, tc = lane & 1;
            int l00 = 8 * tr + 2 * tc;
            v3a = 0.25f * (__shfl(v2a, l00) + __shfl(v2a, l00 + 1) +
                           __shfl(v2a, l00 + 4) + __shfl(v2a, l00 + 5));
            v3b = 0.25f * (__shfl(v2b, l00) + __shfl(v2b, l00 + 1) +
                           __shfl(v2b, l00 + 4) + __shfl(v2b, l00 + 5));
            if (lane < 8) {
                int W8 = W >> 3;
                size_t o = (size_t)((ty >> 3) + tr) * W8 + (tx >> 3) + tc;
                l3a[o] = v3a;
                l3b[o] = v3b;
            }
        }
        {
            int ur = lane & 1;
            float v4a = 0.25f * (__shfl(v3a, 4 * ur) + __shfl(v3a, 4 * ur + 1) +
                                 __shfl(v3a, 4 * ur + 2) + __shfl(v3a, 4 * ur + 3));
            float v4b = 0.25f * (__shfl(v3b, 4 * ur) + __shfl(v3b, 4 * ur + 1) +
                                 __shfl(v3b, 4 * ur + 2) + __shfl(v3b, 4 * ur + 3));
            if (lane < 2) {
                int W16 = W >> 4;
                size_t o = (size_t)((ty >> 4) + ur) * W16 + (tx >> 4);
                l4a[o] = v4a;
                l4b[o] = v4b;
            }
        }
    }

    // ---- Phase 2: horizontal 11-tap, ALL 256 threads, 2 outputs/item ----
    for (int gi = tid; gi < HR * 8; gi += 256) {
        int r  = gi >> 3;
        int c0 = (gi & 7) << 1;
        const float* r1 = &sm->s1[r][c0 + 1];
        const float* r2 = &sm->s2[r][c0 + 1];
        float mua = 0, mva = 0, qua = 0, qva = 0;
        float mub = 0, mvb = 0, qub = 0, qvb = 0;
        #pragma unroll
        for (int k = 0; k < 12; ++k) {              // taps j = c0+1 .. c0+12
            float u = r1[k], v = r2[k];
            float u2 = u * u, v2 = v * v;
            if (k < 11) {
                float gk = g[k];
                mua = fmaf(gk, u,  mua);
                mva = fmaf(gk, v,  mva);
                qua = fmaf(gk, u2, qua);
                qva = fmaf(gk, v2, qva);
            }
            if (k >= 1) {
                float gk = g[k - 1];
                mub = fmaf(gk, u,  mub);
                mvb = fmaf(gk, v,  mvb);
                qub = fmaf(gk, u2, qub);
                qvb = fmaf(gk, v2, qvb);
            }
        }
        *(float2*)&sm->hbuf[r][c0]      = make_float2(mua, mub);
        *(float2*)&sm->hbuf[r][16 + c0] = make_float2(mva, mvb);
        *(float2*)&sm->hbuf[r][32 + c0] = make_float2(qua, qub);
        *(float2*)&sm->hbuf[r][48 + c0] = make_float2(qva, qvb);
    }
    __syncthreads();

    // ---- Phase 3: vertical 11-tap, 128 threads x 4 stacked rows (best measured) ----
    float ssum = 0.f, csum = 0.f;
    if (tid < 128) {
        int c  = tid & 15;              // output col 0..15
        int r0 = (tid >> 4) << 2;       // output rows r0..r0+3
        float MU[4] = {0, 0, 0, 0}, MV[4] = {0, 0, 0, 0};
        float QU[4] = {0, 0, 0, 0}, QV[4] = {0, 0, 0, 0};
        #pragma unroll
        for (int k = 0; k < 14; ++k) {
            const float* hrow = &sm->hbuf[r0 + k][c];
            float h0 = hrow[0];
            float h1 = hrow[16];
            float h2 = hrow[32];
            float h3 = hrow[48];
            #pragma unroll
            for (int j = 0; j < 4; ++j) {
                int t = k - j;
                if (t >= 0 && t < 11) {
                    float gk = g[t];
                    MU[j] = fmaf(gk, h0, MU[j]);
                    MV[j] = fmaf(gk, h1, MV[j]);
                    QU[j] = fmaf(gk, h2, QU[j]);
                    QV[j] = fmaf(gk, h3, QV[j]);
                }
            }
        }
        #pragma unroll
        for (int j = 0; j < 4; ++j) {
            float P = MU[j] * MU[j], Qm = MV[j] * MV[j];
            float A = 0.5f * (P - Qm);            // 2*mu1*mu2
            float B = 0.5f * (P + Qm);            // mu1^2 + mu2^2
            float su = 0.5f * (QU[j] + QV[j]);    // E[x^2] + E[y^2]
            float sd = 0.5f * (QU[j] - QV[j]);    // 2*E[xy]
            float n1 = A + SC1;
            float d1 = B + SC1;
            float n2 = sd - A + SC2;              // 2*sigma12 + C2
            float d2 = su - B + SC2;              // sigma1^2 + sigma2^2 + C2
            float inv = 1.f / (d1 * d2);
            csum += n2 * d1 * inv;
            ssum += n1 * n2 * inv;
        }
    }

    // ---- Block reduction -> one atomic pair per block ----
    #pragma unroll
    for (int off = 32; off; off >>= 1) {
        ssum += __shfl_down(ssum, off);
        csum += __shfl_down(csum, off);
    }
    const int wid = tid >> 6, lane = tid & 63;
    if (lane == 0) { sm->rbuf[wid * 2] = ssum; sm->rbuf[wid * 2 + 1] = csum; }
    __syncthreads();
    if (tid == 0) {
        float S = sm->rbuf[0] + sm->rbuf[2];
        float C = sm->rbuf[1] + sm->rbuf[3];
        int slot = (blockIdx.x + blockIdx.y * 7 + blockIdx.z * 13) & (NSLOT - 1);
        atomicAdd(&accum[(2 * level) * NSLOT + slot], S);
        atomicAdd(&accum[(2 * level + 1) * NSLOT + slot], C);
    }
}

// ---------------- level 0: SSIM + full pyramid -----------------------------
__global__ __launch_bounds__(256, 5) void ssim_l0(
        const float* __restrict__ img1, const float* __restrict__ img2,
        const float* __restrict__ window, float* __restrict__ accum,
        float* __restrict__ l1a, float* __restrict__ l1b,
        float* __restrict__ l2a, float* __restrict__ l2b,
        float* __restrict__ l3a, float* __restrict__ l3b,
        float* __restrict__ l4a, float* __restrict__ l4b)
{
    __shared__ SmemT sm;
    const int plane = blockIdx.z;
    ssim_tile(&sm,
              img1 + (size_t)plane * 512 * 512,
              img2 + (size_t)plane * 512 * 512,
              512, 512, blockIdx.x * TW, blockIdx.y * TH, 0,
              window, accum,
              l1a + (size_t)plane * 256 * 256, l1b + (size_t)plane * 256 * 256,
              l2a + (size_t)plane * 128 * 128, l2b + (size_t)plane * 128 * 128,
              l3a + (size_t)plane * 64 * 64,   l3b + (size_t)plane * 64 * 64,
              l4a + (size_t)plane * 32 * 32,   l4b + (size_t)plane * 32 * 32);
}

// ---------------- combined levels 1-4 (one dispatch) -----------------------
__global__ __launch_bounds__(256, 5) void ssim_rest(
        const float* __restrict__ l1a, const float* __restrict__ l1b,
        const float* __restrict__ l2a, const float* __restrict__ l2b,
        const float* __restrict__ l3a, const float* __restrict__ l3b,
        const float* __restrict__ l4a, const float* __restrict__ l4b,
        const float* __restrict__ window, float* __restrict__ accum)
{
    __shared__ SmemT sm;
    const int x = blockIdx.x;        // 0..169 tile id within plane
    const int plane = blockIdx.z;
    int level, H, tix, tiy;
    const float *b1, *b2;
    if (x < 128)      { level = 1; H = 256; tix = x & 15;            tiy = x >> 4;        b1 = l1a; b2 = l1b; }
    else if (x < 160) { level = 2; H = 128; int i = x - 128; tix = i & 7; tiy = i >> 3;   b1 = l2a; b2 = l2b; }
    else if (x < 168) { level = 3; H = 64;  int i = x - 160; tix = i & 3; tiy = i >> 2;   b1 = l3a; b2 = l3b; }
    else              { level = 4; H = 32;  int i = x - 168; tix = i & 1; tiy = i >> 1;   b1 = l4a; b2 = l4b; }
    const float* p1 = b1 + (size_t)plane * H * H;
    const float* p2 = b2 + (size_t)plane * H * H;
    ssim_tile(&sm, p1, p2, H, H, tix * TW, tiy * TH, level,
              window, accum,
              nullptr, nullptr, nullptr, nullptr,
              nullptr, nullptr, nullptr, nullptr);
}

// ---------------- final weighted product ----------------------------------
__global__ void finalize_kernel(const float* __restrict__ accum, float* __restrict__ out) {
    int t = threadIdx.x;   // 64 threads
    float sums[10];
    #pragma unroll
    for (int i = 0; i < 10; ++i) {
        float v = accum[i * NSLOT + t];
        #pragma unroll
        for (int off = 32; off; off >>= 1) v += __shfl_down(v, off);
        sums[i] = v;
    }
    if (t == 0) {
        const float w[5] = {0.0448f, 0.2856f, 0.3001f, 0.2363f, 0.1333f};
        float res = 1.f;
        #pragma unroll
        for (int L = 0; L < 4; ++L) {
            float dim = (float)(512 >> L);
            float cnt = (float)PLANES * dim * dim;
            res *= powf(sums[2 * L + 1] / cnt, w[L]);   // cs mean, levels 0..3
        }
        float cnt4 = (float)PLANES * 32.f * 32.f;
        res *= powf(sums[8] / cnt4, w[4]);              // ssim mean, level 4
        out[0] = res;
    }
}

// ---------------- launch ---------------------------------------------------
extern "C" void kernel_launch(void* const* d_in, const int* in_sizes, int n_in,
                              void* d_out, int out_size, void* d_ws, size_t ws_size,
                              hipStream_t stream) {
    const float* img1   = (const float*)d_in[0];
    const float* img2   = (const float*)d_in[1];
    const float* window = (const float*)d_in[2];
    float* out = (float*)d_out;
    float* ws  = (float*)d_ws;

    float* accum = ws;   // 640 floats
    const size_t S1 = (size_t)PLANES * 256 * 256;
    const size_t S2 = (size_t)PLANES * 128 * 128;
    const size_t S3 = (size_t)PLANES * 64 * 64;
    const size_t S4 = (size_t)PLANES * 32 * 32;
    float* l1a = ws + 1024;    float* l1b = l1a + S1;
    float* l2a = l1b + S1;     float* l2b = l2a + S2;
    float* l3a = l2b + S2;     float* l3b = l3a + S3;
    float* l4a = l3b + S3;     float* l4b = l4a + S4;

    hipMemsetAsync(accum, 0, 10 * NSLOT * sizeof(float), stream);

    ssim_l0<<<dim3(512 / TW, 512 / TH, PLANES), 256, 0, stream>>>(
        img1, img2, window, accum,
        l1a, l1b, l2a, l2b, l3a, l3b, l4a, l4b);

    ssim_rest<<<dim3(170, 1, PLANES), 256, 0, stream>>>(
        l1a, l1b, l2a, l2b, l3a, l3b, l4a, l4b, window, accum);

    finalize_kernel<<<1, 64, 0, stream>>>(accum, out);
}

// Round 10
// 264.710 us; speedup vs baseline: 1.2453x; 1.2453x over previous
//
#include <hip/hip_runtime.h>
#include <math.h>

#define TW 16                // tile width (output cols)
#define SSTRIDE 29           // s1/s2 row stride: ODD -> conflict-clean b32 (verified r5)
#define HSTRIDE 66           // hbuf row stride: [mu|mv|qu|qv] x16 +pad; ph3 2-way free (verified r9)
#define SC1 0.0001f
#define SC2 0.0009f
#define PLANES 48
#define NSLOT 64

// u/v transform staged at load: s1=u=a+b, s2=v=a-b. 4 windowed quantities
// (mu,mv,qu,qv) recover everything (epilogue verified exact r8/r9).
template<int HRt>
struct SmemT {
    float s1[HRt][SSTRIDE];
    float s2[HRt][SSTRIDE];
    float hbuf[HRt][HSTRIDE];
    float rbuf[8];
};
// THt=32: 20864 B -> 7 blocks/CU.  THt=64: 36736 B -> 4 blocks/CU.

// NOTE: min-waves=6 in __launch_bounds__ forces spill (r3, r5). Use 4-5.
template<int THt>
__device__ __forceinline__ void ssim_tile(
        SmemT<THt + 10>* sm,
        const float* __restrict__ p1, const float* __restrict__ p2,
        int H, int W, int tx, int ty, int level,
        const float* __restrict__ window,
        float* __restrict__ accum,
        float* __restrict__ l1a, float* __restrict__ l1b,   // plane-offset outs (or null)
        float* __restrict__ l2a, float* __restrict__ l2b,
        float* __restrict__ l3a, float* __restrict__ l3b,
        float* __restrict__ l4a, float* __restrict__ l4b)
{
    constexpr int HRt = THt + 10;
    const int tid = threadIdx.x;

    // 1D gaussian from 2D window: g[k] = w2[5][k]/sqrt(w2[5][5])
    float g[11];
    {
        float invg5 = 1.0f / sqrtf(window[60]);
        #pragma unroll
        for (int k = 0; k < 11; ++k) g[k] = window[55 + k] * invg5;
    }

    // ---- Phase 1: stage halo tile (HRt x 28) as u=a+b, v=a-b ----
    for (int s = tid; s < HRt * 14; s += 256) {
        int r = s / 14, j = s - r * 14;
        int gy = ty + r - 5;
        int gx = tx - 6 + 2 * j;
        float2 v1 = make_float2(0.f, 0.f), v2 = make_float2(0.f, 0.f);
        if ((unsigned)gy < (unsigned)H && (unsigned)gx < (unsigned)W) {
            size_t o = (size_t)gy * W + gx;
            v1 = *(const float2*)(p1 + o);
            v2 = *(const float2*)(p2 + o);
        }
        sm->s1[r][2 * j]     = v1.x + v2.x;
        sm->s1[r][2 * j + 1] = v1.y + v2.y;
        sm->s2[r][2 * j]     = v1.x - v2.x;
        sm->s2[r][2 * j + 1] = v1.y - v2.y;
    }
    __syncthreads();

    // ---- Fused 2x2 avg-pool -> l1 (all 256 threads; a=(u+v)/2) ----
    if (l1a) {
        int pc = tid & 7;          // pooled col 0..7
        int pr = tid >> 3;         // pooled row 0..THt/2-1
        int r  = 2 * pr + 5;
        int jj = 2 * pc + 6;
        float su = (sm->s1[r][jj] + sm->s1[r][jj + 1]) +
                   (sm->s1[r + 1][jj] + sm->s1[r + 1][jj + 1]);
        float sv = (sm->s2[r][jj] + sm->s2[r][jj + 1]) +
                   (sm->s2[r + 1][jj] + sm->s2[r + 1][jj + 1]);
        int W2 = W >> 1;
        size_t o = (size_t)((ty >> 1) + pr) * W2 + (tx >> 1) + pc;
        l1a[o] = 0.125f * (su + sv);
        l1b[o] = 0.125f * (su - sv);
    }

    // ---- Pyramid l2/l3/l4 on wave 3 (THt=64: 64 l2 px = full wave) ----
    if (l1a && tid >= 192) {
        const int lane = tid - 192;
        int qr = lane >> 2, qc = lane & 3;      // l2 px = 4x4 mean of originals
        int rb = 4 * qr + 5, cb = 4 * qc + 6;
        float su = 0.f, sv = 0.f;
        #pragma unroll
        for (int i = 0; i < 4; ++i)
            #pragma unroll
            for (int j = 0; j < 4; ++j) {
                su += sm->s1[rb + i][cb + j];
                sv += sm->s2[rb + i][cb + j];
            }
        float v2a = 0.03125f * (su + sv), v2b = 0.03125f * (su - sv);
        {
            int W4 = W >> 2;
            size_t o = (size_t)((ty >> 2) + qr) * W4 + (tx >> 2) + qc;
            l2a[o] = v2a;
            l2b[o] = v2b;
        }
        float v3a, v3b;
        {
            int tr = (lane >> 1) & 7, tc = lane & 1;
            int l00 = 8 * tr + 2 * tc;
            v3a = 0.25f * (__shfl(v2a, l00) + __shfl(v2a, l00 + 1) +
                           __shfl(v2a, l00 + 4) + __shfl(v2a, l00 + 5));
            v3b = 0.25f * (__shfl(v2b, l00) + __shfl(v2b, l00 + 1) +
                           __shfl(v2b, l00 + 4) + __shfl(v2b, l00 + 5));
            if (lane < 16) {
                int W8 = W >> 3;
                size_t o = (size_t)((ty >> 3) + tr) * W8 + (tx >> 3) + tc;
                l3a[o] = v3a;
                l3b[o] = v3b;
            }
        }
        {
            int ur = lane & 3;
            float v4a = 0.25f * (__shfl(v3a, 4 * ur) + __shfl(v3a, 4 * ur + 1) +
                                 __shfl(v3a, 4 * ur + 2) + __shfl(v3a, 4 * ur + 3));
            float v4b = 0.25f * (__shfl(v3b, 4 * ur) + __shfl(v3b, 4 * ur + 1) +
                                 __shfl(v3b, 4 * ur + 2) + __shfl(v3b, 4 * ur + 3));
            if (lane < 4) {
                int W16 = W >> 4;
                size_t o = (size_t)((ty >> 4) + ur) * W16 + (tx >> 4);
                l4a[o] = v4a;
                l4b[o] = v4b;
            }
        }
    }

    // ---- Phase 2: horizontal 11-tap, ALL 256 threads, 2 outputs/item ----
    for (int gi = tid; gi < HRt * 8; gi += 256) {
        int r  = gi >> 3;
        int c0 = (gi & 7) << 1;
        const float* r1 = &sm->s1[r][c0 + 1];
        const float* r2 = &sm->s2[r][c0 + 1];
        float mua = 0, mva = 0, qua = 0, qva = 0;
        float mub = 0, mvb = 0, qub = 0, qvb = 0;
        #pragma unroll
        for (int k = 0; k < 12; ++k) {              // taps j = c0+1 .. c0+12
            float u = r1[k], v = r2[k];
            float u2 = u * u, v2 = v * v;
            if (k < 11) {
                float gk = g[k];
                mua = fmaf(gk, u,  mua);
                mva = fmaf(gk, v,  mva);
                qua = fmaf(gk, u2, qua);
                qva = fmaf(gk, v2, qva);
            }
            if (k >= 1) {
                float gk = g[k - 1];
                mub = fmaf(gk, u,  mub);
                mvb = fmaf(gk, v,  mvb);
                qub = fmaf(gk, u2, qub);
                qvb = fmaf(gk, v2, qvb);
            }
        }
        *(float2*)&sm->hbuf[r][c0]      = make_float2(mua, mub);
        *(float2*)&sm->hbuf[r][16 + c0] = make_float2(mva, mvb);
        *(float2*)&sm->hbuf[r][32 + c0] = make_float2(qua, qub);
        *(float2*)&sm->hbuf[r][48 + c0] = make_float2(qva, qvb);
    }
    __syncthreads();

    // ---- Phase 3: vertical 11-tap, 4*THt threads x 4 stacked rows ----
    float ssum = 0.f, csum = 0.f;
    if (tid < 4 * THt) {
        int c  = tid & 15;              // output col 0..15
        int r0 = (tid >> 4) << 2;       // output rows r0..r0+3
        float MU[4] = {0, 0, 0, 0}, MV[4] = {0, 0, 0, 0};
        float QU[4] = {0, 0, 0, 0}, QV[4] = {0, 0, 0, 0};
        #pragma unroll
        for (int k = 0; k < 14; ++k) {
            const float* hrow = &sm->hbuf[r0 + k][c];
            float h0 = hrow[0];
            float h1 = hrow[16];
            float h2 = hrow[32];
            float h3 = hrow[48];
            #pragma unroll
            for (int j = 0; j < 4; ++j) {
                int t = k - j;
                if (t >= 0 && t < 11) {
                    float gk = g[t];
                    MU[j] = fmaf(gk, h0, MU[j]);
                    MV[j] = fmaf(gk, h1, MV[j]);
                    QU[j] = fmaf(gk, h2, QU[j]);
                    QV[j] = fmaf(gk, h3, QV[j]);
                }
            }
        }
        #pragma unroll
        for (int j = 0; j < 4; ++j) {
            float P = MU[j] * MU[j], Qm = MV[j] * MV[j];
            float A = 0.5f * (P - Qm);            // 2*mu1*mu2
            float B = 0.5f * (P + Qm);            // mu1^2 + mu2^2
            float su = 0.5f * (QU[j] + QV[j]);    // E[x^2] + E[y^2]
            float sd = 0.5f * (QU[j] - QV[j]);    // 2*E[xy]
            float n1 = A + SC1;
            float d1 = B + SC1;
            float n2 = sd - A + SC2;              // 2*sigma12 + C2
            float d2 = su - B + SC2;              // sigma1^2+sigma2^2 + C2
            float inv = 1.f / (d1 * d2);
            csum += n2 * d1 * inv;
            ssum += n1 * n2 * inv;
        }
    }

    // ---- Block reduction -> one atomic pair per block ----
    #pragma unroll
    for (int off = 32; off; off >>= 1) {
        ssum += __shfl_down(ssum, off);
        csum += __shfl_down(csum, off);
    }
    const int wid = tid >> 6, lane = tid & 63;
    if (lane == 0) { sm->rbuf[wid * 2] = ssum; sm->rbuf[wid * 2 + 1] = csum; }
    __syncthreads();
    if (tid == 0) {
        float S = sm->rbuf[0] + sm->rbuf[2] + sm->rbuf[4] + sm->rbuf[6];
        float C = sm->rbuf[1] + sm->rbuf[3] + sm->rbuf[5] + sm->rbuf[7];
        int slot = (blockIdx.x + blockIdx.y * 7 + blockIdx.z * 13) & (NSLOT - 1);
        atomicAdd(&accum[(2 * level) * NSLOT + slot], S);
        atomicAdd(&accum[(2 * level + 1) * NSLOT + slot], C);
    }
}

// ---------------- level 0: 16x64 tiles, SSIM + full pyramid ---------------
__global__ __launch_bounds__(256, 4) void ssim_l0(
        const float* __restrict__ img1, const float* __restrict__ img2,
        const float* __restrict__ window, float* __restrict__ accum,
        float* __restrict__ l1a, float* __restrict__ l1b,
        float* __restrict__ l2a, float* __restrict__ l2b,
        float* __restrict__ l3a, float* __restrict__ l3b,
        float* __restrict__ l4a, float* __restrict__ l4b)
{
    __shared__ SmemT<74> sm;
    const int plane = blockIdx.z;
    ssim_tile<64>(&sm,
              img1 + (size_t)plane * 512 * 512,
              img2 + (size_t)plane * 512 * 512,
              512, 512, blockIdx.x * TW, blockIdx.y * 64, 0,
              window, accum,
              l1a + (size_t)plane * 256 * 256, l1b + (size_t)plane * 256 * 256,
              l2a + (size_t)plane * 128 * 128, l2b + (size_t)plane * 128 * 128,
              l3a + (size_t)plane * 64 * 64,   l3b + (size_t)plane * 64 * 64,
              l4a + (size_t)plane * 32 * 32,   l4b + (size_t)plane * 32 * 32);
}

// ---------------- combined levels 1-4: 16x32 tiles (r9-verified shape) ----
__global__ __launch_bounds__(256, 5) void ssim_rest(
        const float* __restrict__ l1a, const float* __restrict__ l1b,
        const float* __restrict__ l2a, const float* __restrict__ l2b,
        const float* __restrict__ l3a, const float* __restrict__ l3b,
        const float* __restrict__ l4a, const float* __restrict__ l4b,
        const float* __restrict__ window, float* __restrict__ accum)
{
    __shared__ SmemT<42> sm;
    const int x = blockIdx.x;        // 0..169 tile id within plane
    const int plane = blockIdx.z;
    int level, H, tix, tiy;
    const float *b1, *b2;
    if (x < 128)      { level = 1; H = 256; tix = x & 15;            tiy = x >> 4;        b1 = l1a; b2 = l1b; }
    else if (x < 160) { level = 2; H = 128; int i = x - 128; tix = i & 7; tiy = i >> 3;   b1 = l2a; b2 = l2b; }
    else if (x < 168) { level = 3; H = 64;  int i = x - 160; tix = i & 3; tiy = i >> 2;   b1 = l3a; b2 = l3b; }
    else              { level = 4; H = 32;  int i = x - 168; tix = i & 1; tiy = i >> 1;   b1 = l4a; b2 = l4b; }
    const float* p1 = b1 + (size_t)plane * H * H;
    const float* p2 = b2 + (size_t)plane * H * H;
    ssim_tile<32>(&sm, p1, p2, H, H, tix * TW, tiy * 32, level,
              window, accum,
              nullptr, nullptr, nullptr, nullptr,
              nullptr, nullptr, nullptr, nullptr);
}

// ---------------- final weighted product ----------------------------------
__global__ void finalize_kernel(const float* __restrict__ accum, float* __restrict__ out) {
    int t = threadIdx.x;   // 64 threads
    float sums[10];
    #pragma unroll
    for (int i = 0; i < 10; ++i) {
        float v = accum[i * NSLOT + t];
        #pragma unroll
        for (int off = 32; off; off >>= 1) v += __shfl_down(v, off);
        sums[i] = v;
    }
    if (t == 0) {
        const float w[5] = {0.0448f, 0.2856f, 0.3001f, 0.2363f, 0.1333f};
        float res = 1.f;
        #pragma unroll
        for (int L = 0; L < 4; ++L) {
            float dim = (float)(512 >> L);
            float cnt = (float)PLANES * dim * dim;
            res *= powf(sums[2 * L + 1] / cnt, w[L]);   // cs mean, levels 0..3
        }
        float cnt4 = (float)PLANES * 32.f * 32.f;
        res *= powf(sums[8] / cnt4, w[4]);              // ssim mean, level 4
        out[0] = res;
    }
}

// ---------------- launch ---------------------------------------------------
extern "C" void kernel_launch(void* const* d_in, const int* in_sizes, int n_in,
                              void* d_out, int out_size, void* d_ws, size_t ws_size,
                              hipStream_t stream) {
    const float* img1   = (const float*)d_in[0];
    const float* img2   = (const float*)d_in[1];
    const float* window = (const float*)d_in[2];
    float* out = (float*)d_out;
    float* ws  = (float*)d_ws;

    float* accum = ws;   // 640 floats
    const size_t S1 = (size_t)PLANES * 256 * 256;
    const size_t S2 = (size_t)PLANES * 128 * 128;
    const size_t S3 = (size_t)PLANES * 64 * 64;
    const size_t S4 = (size_t)PLANES * 32 * 32;
    float* l1a = ws + 1024;    float* l1b = l1a + S1;
    float* l2a = l1b + S1;     float* l2b = l2a + S2;
    float* l3a = l2b + S2;     float* l3b = l3a + S3;
    float* l4a = l3b + S3;     float* l4b = l4a + S4;

    hipMemsetAsync(accum, 0, 10 * NSLOT * sizeof(float), stream);

    ssim_l0<<<dim3(512 / TW, 512 / 64, PLANES), 256, 0, stream>>>(
        img1, img2, window, accum,
        l1a, l1b, l2a, l2b, l3a, l3b, l4a, l4b);

    ssim_rest<<<dim3(170, 1, PLANES), 256, 0, stream>>>(
        l1a, l1b, l2a, l2b, l3a, l3b, l4a, l4b, window, accum);

    finalize_kernel<<<1, 64, 0, stream>>>(accum, out);
}